// Round 18
// baseline (165.330 us; speedup 1.0000x reference)
//
#include <hip/hip_runtime.h>
#include <hip/hip_bf16.h>
#include <hip/hip_fp16.h>

#define N_NODES 50000
#define N_EDGES 800000
#define IN_F 256
#define NH 4
#define DH 64
#define HD 256
#define ALPHA 0.2f
#define EPB 16384                                  // edges per hist block (2^14)
#define NHB ((N_EDGES + EPB - 1) / EPB)            // 49 hist blocks / copies

typedef short bf16x8 __attribute__((ext_vector_type(8)));
typedef float f32x4 __attribute__((ext_vector_type(4)));

__device__ __forceinline__ unsigned short f2bf(float f) {
    unsigned u = __float_as_uint(f);
    u = (u + 0x7FFFu + ((u >> 16) & 1u)) >> 16;   // RNE
    return (unsigned short)u;
}

// ---------------- cvt: Bt transpose-convert ----------------
__global__ __launch_bounds__(256) void k_cvt(const float* __restrict__ fw,
                                             unsigned short* __restrict__ Bt) {
    int n = blockIdx.x;            // 0..255
    int k = threadIdx.x;           // 0..255
    Bt[n * 256 + k] = f2bf(fw[k * 256 + n]);
}

// ---------------- hist: LDS counting (packed 2xu16), no global atomics ----------
// Block b owns edges [b*EPB, b*EPB+EPB). Full node histogram lives in LDS
// (25000 ints = 100 KB). LDS atomicAdd returns the edge's rank within its
// (block, dst) bucket -> erank[e]. Unpack LDS -> hist[b][node] (fully written,
// no memset needed).
__global__ __launch_bounds__(1024) void k_hist(const int* __restrict__ dst,
                                               int* __restrict__ hist,
                                               int* __restrict__ erank) {
    __shared__ int cnt[N_NODES / 2];               // 100 KB
    const int t = threadIdx.x;
    const int b = blockIdx.x;
    for (int i = t; i < N_NODES / 2; i += 1024) cnt[i] = 0;
    __syncthreads();
    const int e0 = b * EPB;
    const int eend = min(e0 + EPB, N_EDGES);
    for (int e = e0 + t; e < eend; e += 1024) {
        int d = dst[e];
        int old = atomicAdd(&cnt[d >> 1], (d & 1) ? (1 << 16) : 1);
        erank[e] = (d & 1) ? ((old >> 16) & 0xffff) : (old & 0xffff);
    }
    __syncthreads();
    int* hb = hist + (size_t)b * N_NODES;
    for (int i = t; i < N_NODES / 2; i += 1024) {
        int v = cnt[i];
        int2 o; o.x = v & 0xffff; o.y = ((unsigned)v) >> 16;
        *(int2*)(hb + 2 * i) = o;
    }
}

// ---------------- GEMM: fth = f16( feat @ fc_w ) + fused el/er (pure) ----------
// BM=128, BN=256 (full), 512 threads = 8 waves (2M x 4N); B staged once in LDS
// (XOR-swizzled, 128 KB). Swapped-operand MFMA -> lane&15 = output ROW -> direct
// packed f16 stores + in-register el/er. One barrier total.
__global__ __launch_bounds__(512) void k_gemm(const float* __restrict__ A,
                                              const unsigned short* __restrict__ Bt,
                                              unsigned short* __restrict__ fth,
                                              float* __restrict__ el,
                                              float* __restrict__ er,
                                              const float* __restrict__ al,
                                              const float* __restrict__ ar, int M) {
    __shared__ __align__(16) char smem[131072];   // B-tile 256x256 bf16, swizzled
    const int tid = threadIdx.x;
    const int m0 = blockIdx.x * 128;

    #pragma unroll
    for (int c = 0; c < 16; c++) {
        int o = c * 8192 + tid * 16;            // byte offset
        bf16x8 v = *(const bf16x8*)((const char*)Bt + o);
        int nl = o >> 9;
        int lb = o ^ ((nl & 7) << 4);
        *(bf16x8*)(smem + lb) = v;
    }
    __syncthreads();

    const int w = tid >> 6, lane = tid & 63;
    const int wm = w >> 2, wn = w & 3;          // 2 x 4; wave's 64-col slice = head wn
    const int fr = lane & 15, quad = lane >> 4;

    const float* arow[4];
    int gm[4];
    #pragma unroll
    for (int j = 0; j < 4; j++) {
        gm[j] = m0 + wm * 64 + j * 16 + fr;
        int cr = gm[j] < M ? gm[j] : (M - 1);
        arow[j] = A + (size_t)cr * IN_F;
    }

    f32x4 acc[4][4];
    #pragma unroll
    for (int j = 0; j < 4; j++)
        #pragma unroll
        for (int f = 0; f < 4; f++) acc[j][f] = (f32x4){0.f, 0.f, 0.f, 0.f};

    #pragma unroll
    for (int kk = 0; kk < 8; kk++) {
        bf16x8 af[4];
        #pragma unroll
        for (int j = 0; j < 4; j++) {
            float4 lo = *(const float4*)(arow[j] + kk * 32 + quad * 8);
            float4 hi = *(const float4*)(arow[j] + kk * 32 + quad * 8 + 4);
            af[j][0] = (short)f2bf(lo.x); af[j][1] = (short)f2bf(lo.y);
            af[j][2] = (short)f2bf(lo.z); af[j][3] = (short)f2bf(lo.w);
            af[j][4] = (short)f2bf(hi.x); af[j][5] = (short)f2bf(hi.y);
            af[j][6] = (short)f2bf(hi.z); af[j][7] = (short)f2bf(hi.w);
        }
        #pragma unroll
        for (int f = 0; f < 4; f++) {
            int nl = wn * 64 + f * 16 + fr;
            int lb = (nl * 512 + (kk * 32 + quad * 8) * 2) ^ ((nl & 7) << 4);
            bf16x8 bfr = *(const bf16x8*)(smem + lb);
            #pragma unroll
            for (int j = 0; j < 4; j++)
                acc[j][f] = __builtin_amdgcn_mfma_f32_16x16x32_bf16(bfr, af[j], acc[j][f], 0, 0, 0);
        }
    }
    // lane holds D[row = m0+wm*64+j*16+fr][col = wn*64+f*16+quad*4+r]

    // fused el/er (head wn)
    #pragma unroll
    for (int j = 0; j < 4; j++) {
        float pl = 0.f, pr = 0.f;
        #pragma unroll
        for (int f = 0; f < 4; f++) {
            float4 a4 = *(const float4*)(al + wn * 64 + f * 16 + quad * 4);
            float4 b4 = *(const float4*)(ar + wn * 64 + f * 16 + quad * 4);
            pl += acc[j][f][0] * a4.x + acc[j][f][1] * a4.y + acc[j][f][2] * a4.z + acc[j][f][3] * a4.w;
            pr += acc[j][f][0] * b4.x + acc[j][f][1] * b4.y + acc[j][f][2] * b4.z + acc[j][f][3] * b4.w;
        }
        pl += __shfl_xor(pl, 16); pl += __shfl_xor(pl, 32);
        pr += __shfl_xor(pr, 16); pr += __shfl_xor(pr, 32);
        if (quad == 0 && gm[j] < M) {
            el[gm[j] * NH + wn] = pl;
            er[gm[j] * NH + wn] = pr;
        }
    }

    // direct f16 stores
    #pragma unroll
    for (int j = 0; j < 4; j++) {
        if (gm[j] < M) {
            unsigned short* dp = fth + (size_t)gm[j] * HD + wn * 64 + quad * 4;
            #pragma unroll
            for (int f = 0; f < 4; f++) {
                ushort4 pk;
                pk.x = __half_as_ushort(__float2half(acc[j][f][0]));
                pk.y = __half_as_ushort(__float2half(acc[j][f][1]));
                pk.z = __half_as_ushort(__float2half(acc[j][f][2]));
                pk.w = __half_as_ushort(__float2half(acc[j][f][3]));
                *(ushort4*)(dp + f * 16) = pk;
            }
        }
    }
}

// ---------------- CSR scan: merge NHB copies -> counts, per-copy exclusive prefix ----
__global__ __launch_bounds__(512) void k_scan1(int* __restrict__ hist,
                                               int* __restrict__ counts,
                                               int* __restrict__ incl,
                                               int* __restrict__ bsum, int N) {
    __shared__ int sm[512];
    int i = blockIdx.x * 512 + threadIdx.x;
    int v = 0;
    if (i < N) {
        int pf = 0;
        for (int c = 0; c < NHB; c++) {
            int t = hist[(size_t)c * N_NODES + i];
            hist[(size_t)c * N_NODES + i] = pf;  // exclusive prefix over copies
            pf += t;
        }
        v = pf;
        counts[i] = v;
    }
    sm[threadIdx.x] = v;
    __syncthreads();
    for (int off = 1; off < 512; off <<= 1) {
        int t = (threadIdx.x >= off) ? sm[threadIdx.x - off] : 0;
        __syncthreads();
        sm[threadIdx.x] += t;
        __syncthreads();
    }
    if (i < N) incl[i] = sm[threadIdx.x];
    if (threadIdx.x == 511) bsum[blockIdx.x] = sm[511];
}

// scan3: offs[i] computed AND folded into the NHB per-copy prefixes.
__global__ __launch_bounds__(256) void k_scan3(const int* __restrict__ counts,
                                               const int* __restrict__ incl,
                                               const int* __restrict__ bsum,
                                               int* __restrict__ offs,
                                               int* __restrict__ hist, int N) {
    __shared__ int sprefix;
    int nb = blockIdx.x >> 1;
    if (threadIdx.x < 64) {
        int v = 0;
        for (int j = threadIdx.x; j < nb; j += 64) v += bsum[j];
        #pragma unroll
        for (int off = 1; off < 64; off <<= 1) v += __shfl_xor(v, off);
        if (threadIdx.x == 0) sprefix = v;
    }
    __syncthreads();
    int i = blockIdx.x * 256 + threadIdx.x;
    if (i < N) {
        int o = incl[i] - counts[i] + sprefix;
        offs[i] = o;
        for (int c = 0; c < NHB; c++) hist[(size_t)c * N_NODES + i] += o;
    }
}

// ---------------- scatter: atomic-free, single random gather ----------------
__global__ __launch_bounds__(256) void k_scatter(const int* __restrict__ src,
                                                 const int* __restrict__ dst,
                                                 const int* __restrict__ prefix,
                                                 const int* __restrict__ erank,
                                                 int* __restrict__ esrc) {
    int e = blockIdx.x * 256 + threadIdx.x;
    if (e < N_EDGES) {
        int d = dst[e];
        int c = e >> 14;                         // same block mapping as k_hist
        int p = prefix[(size_t)c * N_NODES + d] + erank[e];
        esrc[p] = src[e];
    }
}

// ---------------- Aggregation: one wave per dst node, SINGLE PASS ----------------
__global__ __launch_bounds__(256) void k_agg(const unsigned short* __restrict__ fth,
                                             const float* __restrict__ el,
                                             const float* __restrict__ er,
                                             const int* __restrict__ offs,
                                             const int* __restrict__ counts,
                                             const int* __restrict__ esrc,
                                             float* __restrict__ out, int N) {
    int wid = (blockIdx.x * 256 + threadIdx.x) >> 6;
    const int lane = threadIdx.x & 63;
    if (wid >= N) return;
    const int deg = counts[wid];
    const int start = offs[wid];
    const int quad = lane >> 4;                 // head of my 4 cols
    const float erq = er[wid * NH + quad];

    float s = 0.f;
    float a0 = 0.f, a1 = 0.f, a2 = 0.f, a3 = 0.f;
    #pragma unroll 4
    for (int i = 0; i < deg; i++) {
        int sv = esrc[start + i];                     // wave-uniform
        float x = el[sv * NH + quad] + erq;           // 1-line broadcast gather
        x = (x > 0.f) ? x : ALPHA * x;
        float wgt = __expf(x);
        s += wgt;
        float2 raw = ((const float2*)fth)[(size_t)sv * 64 + lane];
        __half2 h0 = *reinterpret_cast<const __half2*>(&raw.x);
        __half2 h1 = *reinterpret_cast<const __half2*>(&raw.y);
        a0 = fmaf(wgt, __low2float(h0), a0);
        a1 = fmaf(wgt, __high2float(h0), a1);
        a2 = fmaf(wgt, __low2float(h1), a2);
        a3 = fmaf(wgt, __high2float(h1), a3);
    }
    float invd = (deg > 0 && s > 0.f) ? 1.f / s : 0.f;
    f32x4 o;
    o[0] = a0 * invd; o[1] = a1 * invd; o[2] = a2 * invd; o[3] = a3 * invd;
    __builtin_nontemporal_store(o, (f32x4*)out + (size_t)wid * 64 + lane);
}

// ---------------- launch ----------------
extern "C" void kernel_launch(void* const* d_in, const int* in_sizes, int n_in,
                              void* d_out, int out_size, void* d_ws, size_t ws_size,
                              hipStream_t stream) {
    const float* feat = (const float*)d_in[0];
    const float* fc_w = (const float*)d_in[1];
    const float* attn_l = (const float*)d_in[2];
    const float* attn_r = (const float*)d_in[3];
    const int* src = (const int*)d_in[4];
    const int* dst = (const int*)d_in[5];
    float* out = (float*)d_out;

    char* w = (char*)d_ws;
    unsigned short* fth = (unsigned short*)w;  w += (size_t)N_NODES * HD * 2;      // 25.6 MB (f16)
    unsigned short* Bt = (unsigned short*)w;   w += (size_t)IN_F * HD * 2;         // 128 KB (bf16)
    float* el = (float*)w;       w += (size_t)N_NODES * NH * 4;                    // 800 KB
    float* er = (float*)w;       w += (size_t)N_NODES * NH * 4;                    // 800 KB
    int* hist = (int*)w;         w += (size_t)NHB * N_NODES * 4;                   // 9.8 MB
    int* counts = (int*)w;       w += (size_t)N_NODES * 4;
    int* incl = (int*)w;         w += (size_t)N_NODES * 4;
    int* offs = (int*)w;         w += (size_t)N_NODES * 4;
    int* bsum = (int*)w;         w += 1024;
    int* erank = (int*)w;        w += (size_t)N_EDGES * 4;                          // 3.2 MB
    int* esrc = (int*)w;         w += (size_t)N_EDGES * 4;                          // 3.2 MB

    k_cvt<<<256, 256, 0, stream>>>(fc_w, Bt);

    k_hist<<<NHB, 1024, 0, stream>>>(dst, hist, erank);

    k_gemm<<<(N_NODES + 127) / 128, 512, 0, stream>>>(feat, Bt, fth, el, er,
                                                      attn_l, attn_r, N_NODES);

    int nsb = (N_NODES + 511) / 512;
    k_scan1<<<nsb, 512, 0, stream>>>(hist, counts, incl, bsum, N_NODES);
    k_scan3<<<(N_NODES + 255) / 256, 256, 0, stream>>>(counts, incl, bsum, offs, hist, N_NODES);

    int eblocks = (N_EDGES + 255) / 256;
    k_scatter<<<eblocks, 256, 0, stream>>>(src, dst, hist, erank, esrc);

    int agg_blocks = (N_NODES * 64 + 255) / 256;
    k_agg<<<agg_blocks, 256, 0, stream>>>(fth, el, er, offs, counts, esrc, out, N_NODES);
}

// Round 19
// 146.282 us; speedup vs baseline: 1.1302x; 1.1302x over previous
//
#include <hip/hip_runtime.h>
#include <hip/hip_bf16.h>
#include <hip/hip_fp16.h>

#define N_NODES 50000
#define N_EDGES 800000
#define IN_F 256
#define NH 4
#define DH 64
#define HD 256
#define ALPHA 0.2f
#define EPB 16384                                  // edges per hist block (2^14)
#define NHB ((N_EDGES + EPB - 1) / EPB)            // 49 hist blocks / copies
#define GEMMB ((N_NODES + 127) / 128)              // 391 gemm blocks

typedef short bf16x8 __attribute__((ext_vector_type(8)));
typedef float f32x4 __attribute__((ext_vector_type(4)));

__device__ __forceinline__ unsigned short f2bf(float f) {
    unsigned u = __float_as_uint(f);
    u = (u + 0x7FFFu + ((u >> 16) & 1u)) >> 16;   // RNE
    return (unsigned short)u;
}

// ---------------- cvt: Bt transpose-convert ----------------
__global__ __launch_bounds__(256) void k_cvt(const float* __restrict__ fw,
                                             unsigned short* __restrict__ Bt) {
    int n = blockIdx.x;            // 0..255
    int k = threadIdx.x;           // 0..255
    Bt[n * 256 + k] = f2bf(fw[k * 256 + n]);
}

// ---------------- MAIN: blocks 0..48 = LDS-hist, blocks 49.. = GEMM tile --------
// HIST: block b owns edges [b*EPB, b*EPB+EPB); full node histogram in LDS as
// packed 2xu16 (100 KB of the 128 KB block LDS). LDS atomicAdd returns the
// edge's rank -> erank[e]; unpack -> hist[b][node]. No global atomics -> no
// fabric interference with gemm blocks.
// GEMM: BM=128, BN=256, 512 thr = 8 waves (2M x 4N); B staged once in LDS
// (XOR-swizzled, 128 KB). Swapped-operand MFMA -> direct packed f16 stores +
// in-register el/er.
__global__ __launch_bounds__(512) void k_main(const float* __restrict__ A,
                                              const unsigned short* __restrict__ Bt,
                                              unsigned short* __restrict__ fth,
                                              float* __restrict__ el,
                                              float* __restrict__ er,
                                              const float* __restrict__ al,
                                              const float* __restrict__ ar,
                                              const int* __restrict__ dst,
                                              int* __restrict__ hist,
                                              int* __restrict__ erank, int M) {
    __shared__ __align__(16) char smem[131072];
    const int tid = threadIdx.x;

    if (blockIdx.x < NHB) {
        // -------- histogram block (LDS counting, packed 2xu16) --------
        int* cnt = (int*)smem;                     // 100 KB used
        const int b = blockIdx.x;
        for (int i = tid; i < N_NODES / 2; i += 512) cnt[i] = 0;
        __syncthreads();
        const int e0 = b * EPB;
        const int eend = min(e0 + EPB, N_EDGES);
        for (int e = e0 + tid; e < eend; e += 512) {
            int d = dst[e];
            int old = atomicAdd(&cnt[d >> 1], (d & 1) ? (1 << 16) : 1);
            erank[e] = (d & 1) ? ((old >> 16) & 0xffff) : (old & 0xffff);
        }
        __syncthreads();
        int* hb = hist + (size_t)b * N_NODES;
        for (int i = tid; i < N_NODES / 2; i += 512) {
            int v = cnt[i];
            int2 o; o.x = v & 0xffff; o.y = ((unsigned)v) >> 16;
            *(int2*)(hb + 2 * i) = o;
        }
        return;
    }

    // -------- GEMM block --------
    const int m0 = (blockIdx.x - NHB) * 128;

    #pragma unroll
    for (int c = 0; c < 16; c++) {
        int o = c * 8192 + tid * 16;            // byte offset
        bf16x8 v = *(const bf16x8*)((const char*)Bt + o);
        int nl = o >> 9;
        int lb = o ^ ((nl & 7) << 4);
        *(bf16x8*)(smem + lb) = v;
    }
    __syncthreads();

    const int w = tid >> 6, lane = tid & 63;
    const int wm = w >> 2, wn = w & 3;          // 2 x 4; wave's 64-col slice = head wn
    const int fr = lane & 15, quad = lane >> 4;

    const float* arow[4];
    int gm[4];
    #pragma unroll
    for (int j = 0; j < 4; j++) {
        gm[j] = m0 + wm * 64 + j * 16 + fr;
        int cr = gm[j] < M ? gm[j] : (M - 1);
        arow[j] = A + (size_t)cr * IN_F;
    }

    f32x4 acc[4][4];
    #pragma unroll
    for (int j = 0; j < 4; j++)
        #pragma unroll
        for (int f = 0; f < 4; f++) acc[j][f] = (f32x4){0.f, 0.f, 0.f, 0.f};

    #pragma unroll
    for (int kk = 0; kk < 8; kk++) {
        bf16x8 af[4];
        #pragma unroll
        for (int j = 0; j < 4; j++) {
            float4 lo = *(const float4*)(arow[j] + kk * 32 + quad * 8);
            float4 hi = *(const float4*)(arow[j] + kk * 32 + quad * 8 + 4);
            af[j][0] = (short)f2bf(lo.x); af[j][1] = (short)f2bf(lo.y);
            af[j][2] = (short)f2bf(lo.z); af[j][3] = (short)f2bf(lo.w);
            af[j][4] = (short)f2bf(hi.x); af[j][5] = (short)f2bf(hi.y);
            af[j][6] = (short)f2bf(hi.z); af[j][7] = (short)f2bf(hi.w);
        }
        #pragma unroll
        for (int f = 0; f < 4; f++) {
            int nl = wn * 64 + f * 16 + fr;
            int lb = (nl * 512 + (kk * 32 + quad * 8) * 2) ^ ((nl & 7) << 4);
            bf16x8 bfr = *(const bf16x8*)(smem + lb);
            #pragma unroll
            for (int j = 0; j < 4; j++)
                acc[j][f] = __builtin_amdgcn_mfma_f32_16x16x32_bf16(bfr, af[j], acc[j][f], 0, 0, 0);
        }
    }
    // lane holds D[row = m0+wm*64+j*16+fr][col = wn*64+f*16+quad*4+r]

    // fused el/er (head wn)
    #pragma unroll
    for (int j = 0; j < 4; j++) {
        float pl = 0.f, pr = 0.f;
        #pragma unroll
        for (int f = 0; f < 4; f++) {
            float4 a4 = *(const float4*)(al + wn * 64 + f * 16 + quad * 4);
            float4 b4 = *(const float4*)(ar + wn * 64 + f * 16 + quad * 4);
            pl += acc[j][f][0] * a4.x + acc[j][f][1] * a4.y + acc[j][f][2] * a4.z + acc[j][f][3] * a4.w;
            pr += acc[j][f][0] * b4.x + acc[j][f][1] * b4.y + acc[j][f][2] * b4.z + acc[j][f][3] * b4.w;
        }
        pl += __shfl_xor(pl, 16); pl += __shfl_xor(pl, 32);
        pr += __shfl_xor(pr, 16); pr += __shfl_xor(pr, 32);
        if (quad == 0 && gm[j] < M) {
            el[gm[j] * NH + wn] = pl;
            er[gm[j] * NH + wn] = pr;
        }
    }

    // direct f16 stores
    #pragma unroll
    for (int j = 0; j < 4; j++) {
        if (gm[j] < M) {
            unsigned short* dp = fth + (size_t)gm[j] * HD + wn * 64 + quad * 4;
            #pragma unroll
            for (int f = 0; f < 4; f++) {
                ushort4 pk;
                pk.x = __half_as_ushort(__float2half(acc[j][f][0]));
                pk.y = __half_as_ushort(__float2half(acc[j][f][1]));
                pk.z = __half_as_ushort(__float2half(acc[j][f][2]));
                pk.w = __half_as_ushort(__float2half(acc[j][f][3]));
                *(ushort4*)(dp + f * 16) = pk;
            }
        }
    }
}

// ---------------- CSR scan: merge NHB copies -> counts, per-copy exclusive prefix ----
__global__ __launch_bounds__(512) void k_scan1(int* __restrict__ hist,
                                               int* __restrict__ counts,
                                               int* __restrict__ incl,
                                               int* __restrict__ bsum, int N) {
    __shared__ int sm[512];
    int i = blockIdx.x * 512 + threadIdx.x;
    int v = 0;
    if (i < N) {
        int pf = 0;
        for (int c = 0; c < NHB; c++) {
            int t = hist[(size_t)c * N_NODES + i];
            hist[(size_t)c * N_NODES + i] = pf;  // exclusive prefix over copies
            pf += t;
        }
        v = pf;
        counts[i] = v;
    }
    sm[threadIdx.x] = v;
    __syncthreads();
    for (int off = 1; off < 512; off <<= 1) {
        int t = (threadIdx.x >= off) ? sm[threadIdx.x - off] : 0;
        __syncthreads();
        sm[threadIdx.x] += t;
        __syncthreads();
    }
    if (i < N) incl[i] = sm[threadIdx.x];
    if (threadIdx.x == 511) bsum[blockIdx.x] = sm[511];
}

// scan3: offs only (no fold; scatter gathers offs[d] separately, L2-hot)
__global__ __launch_bounds__(256) void k_scan3(const int* __restrict__ counts,
                                               const int* __restrict__ incl,
                                               const int* __restrict__ bsum,
                                               int* __restrict__ offs, int N) {
    __shared__ int sprefix;
    int nb = blockIdx.x >> 1;
    if (threadIdx.x < 64) {
        int v = 0;
        for (int j = threadIdx.x; j < nb; j += 64) v += bsum[j];
        #pragma unroll
        for (int off = 1; off < 64; off <<= 1) v += __shfl_xor(v, off);
        if (threadIdx.x == 0) sprefix = v;
    }
    __syncthreads();
    int i = blockIdx.x * 256 + threadIdx.x;
    if (i < N) offs[i] = incl[i] - counts[i] + sprefix;
}

// ---------------- scatter: atomic-free, two L2-hot gathers ----------------
__global__ __launch_bounds__(256) void k_scatter(const int* __restrict__ src,
                                                 const int* __restrict__ dst,
                                                 const int* __restrict__ hist,
                                                 const int* __restrict__ offs,
                                                 const int* __restrict__ erank,
                                                 int* __restrict__ esrc) {
    int e = blockIdx.x * 256 + threadIdx.x;
    if (e < N_EDGES) {
        int d = dst[e];
        int c = e >> 14;                         // same block mapping as hist
        int p = hist[(size_t)c * N_NODES + d] + offs[d] + erank[e];
        esrc[p] = src[e];
    }
}

// ---------------- Aggregation: one wave per dst node, SINGLE PASS ----------------
__global__ __launch_bounds__(256) void k_agg(const unsigned short* __restrict__ fth,
                                             const float* __restrict__ el,
                                             const float* __restrict__ er,
                                             const int* __restrict__ offs,
                                             const int* __restrict__ counts,
                                             const int* __restrict__ esrc,
                                             float* __restrict__ out, int N) {
    int wid = (blockIdx.x * 256 + threadIdx.x) >> 6;
    const int lane = threadIdx.x & 63;
    if (wid >= N) return;
    const int deg = counts[wid];
    const int start = offs[wid];
    const int quad = lane >> 4;                 // head of my 4 cols
    const float erq = er[wid * NH + quad];

    float s = 0.f;
    float a0 = 0.f, a1 = 0.f, a2 = 0.f, a3 = 0.f;
    #pragma unroll 4
    for (int i = 0; i < deg; i++) {
        int sv = esrc[start + i];                     // wave-uniform
        float x = el[sv * NH + quad] + erq;           // 1-line broadcast gather
        x = (x > 0.f) ? x : ALPHA * x;
        float wgt = __expf(x);
        s += wgt;
        float2 raw = ((const float2*)fth)[(size_t)sv * 64 + lane];
        __half2 h0 = *reinterpret_cast<const __half2*>(&raw.x);
        __half2 h1 = *reinterpret_cast<const __half2*>(&raw.y);
        a0 = fmaf(wgt, __low2float(h0), a0);
        a1 = fmaf(wgt, __high2float(h0), a1);
        a2 = fmaf(wgt, __low2float(h1), a2);
        a3 = fmaf(wgt, __high2float(h1), a3);
    }
    float invd = (deg > 0 && s > 0.f) ? 1.f / s : 0.f;
    f32x4 o;
    o[0] = a0 * invd; o[1] = a1 * invd; o[2] = a2 * invd; o[3] = a3 * invd;
    __builtin_nontemporal_store(o, (f32x4*)out + (size_t)wid * 64 + lane);
}

// ---------------- launch ----------------
extern "C" void kernel_launch(void* const* d_in, const int* in_sizes, int n_in,
                              void* d_out, int out_size, void* d_ws, size_t ws_size,
                              hipStream_t stream) {
    const float* feat = (const float*)d_in[0];
    const float* fc_w = (const float*)d_in[1];
    const float* attn_l = (const float*)d_in[2];
    const float* attn_r = (const float*)d_in[3];
    const int* src = (const int*)d_in[4];
    const int* dst = (const int*)d_in[5];
    float* out = (float*)d_out;

    char* w = (char*)d_ws;
    unsigned short* fth = (unsigned short*)w;  w += (size_t)N_NODES * HD * 2;      // 25.6 MB (f16)
    unsigned short* Bt = (unsigned short*)w;   w += (size_t)IN_F * HD * 2;         // 128 KB (bf16)
    float* el = (float*)w;       w += (size_t)N_NODES * NH * 4;                    // 800 KB
    float* er = (float*)w;       w += (size_t)N_NODES * NH * 4;                    // 800 KB
    int* hist = (int*)w;         w += (size_t)NHB * N_NODES * 4;                   // 9.8 MB
    int* counts = (int*)w;       w += (size_t)N_NODES * 4;
    int* incl = (int*)w;         w += (size_t)N_NODES * 4;
    int* offs = (int*)w;         w += (size_t)N_NODES * 4;
    int* bsum = (int*)w;         w += 1024;
    int* erank = (int*)w;        w += (size_t)N_EDGES * 4;                          // 3.2 MB
    int* esrc = (int*)w;         w += (size_t)N_EDGES * 4;                          // 3.2 MB

    k_cvt<<<256, 256, 0, stream>>>(fc_w, Bt);

    // main: 49 hist blocks + 391 gemm blocks, one dispatch
    k_main<<<NHB + GEMMB, 512, 0, stream>>>(feat, Bt, fth, el, er, attn_l, attn_r,
                                            dst, hist, erank, N_NODES);

    int nsb = (N_NODES + 511) / 512;
    k_scan1<<<nsb, 512, 0, stream>>>(hist, counts, incl, bsum, N_NODES);
    k_scan3<<<(N_NODES + 255) / 256, 256, 0, stream>>>(counts, incl, bsum, offs, N_NODES);

    int eblocks = (N_EDGES + 255) / 256;
    k_scatter<<<eblocks, 256, 0, stream>>>(src, dst, hist, offs, erank, esrc);

    int agg_blocks = (N_NODES * 64 + 255) / 256;
    k_agg<<<agg_blocks, 256, 0, stream>>>(fth, el, er, offs, counts, esrc, out, N_NODES);
}

// Round 20
// 145.696 us; speedup vs baseline: 1.1348x; 1.0040x over previous
//
#include <hip/hip_runtime.h>
#include <hip/hip_bf16.h>
#include <hip/hip_fp16.h>

#define N_NODES 50000
#define N_EDGES 800000
#define IN_F 256
#define NH 4
#define DH 64
#define HD 256
#define ALPHA 0.2f
#define EPB 16384                                  // edges per hist block (2^14)
#define NHB ((N_EDGES + EPB - 1) / EPB)            // 49 hist blocks / copies
#define GEMMB ((N_NODES + 255) / 256)              // 196 gemm blocks (BM=256)

typedef short bf16x8 __attribute__((ext_vector_type(8)));
typedef float f32x4 __attribute__((ext_vector_type(4)));

__device__ __forceinline__ unsigned short f2bf(float f) {
    unsigned u = __float_as_uint(f);
    u = (u + 0x7FFFu + ((u >> 16) & 1u)) >> 16;   // RNE
    return (unsigned short)u;
}

// ---------------- cvt: Bt transpose-convert ----------------
__global__ __launch_bounds__(256) void k_cvt(const float* __restrict__ fw,
                                             unsigned short* __restrict__ Bt) {
    int n = blockIdx.x;            // 0..255
    int k = threadIdx.x;           // 0..255
    Bt[n * 256 + k] = f2bf(fw[k * 256 + n]);
}

// ---------------- MAIN: blocks 0..48 = LDS-hist, blocks 49.. = GEMM tile --------
// HIST: block b owns edges [b*EPB, b*EPB+EPB); full node histogram in LDS as
// packed 2xu16 (100 KB). LDS atomicAdd returns rank -> erank[e]; unpack ->
// hist[b][node]. No global atomics.
// GEMM: BM=256, BN=256 (full), 512 thr = 8 waves (2M x 4N, 128 rows/wave);
// B staged once in LDS (XOR-swizzled, 128 KB; 25 MB total vs 50 at BM=128).
// 196+49 = 245 blocks = ONE scheduling round at 1 block/CU.
__global__ __launch_bounds__(512) void k_main(const float* __restrict__ A,
                                              const unsigned short* __restrict__ Bt,
                                              unsigned short* __restrict__ fth,
                                              float* __restrict__ el,
                                              float* __restrict__ er,
                                              const float* __restrict__ al,
                                              const float* __restrict__ ar,
                                              const int* __restrict__ dst,
                                              int* __restrict__ hist,
                                              int* __restrict__ erank, int M) {
    __shared__ __align__(16) char smem[131072];
    const int tid = threadIdx.x;

    if (blockIdx.x < NHB) {
        // -------- histogram block (LDS counting, packed 2xu16) --------
        int* cnt = (int*)smem;                     // 100 KB used
        const int b = blockIdx.x;
        for (int i = tid; i < N_NODES / 2; i += 512) cnt[i] = 0;
        __syncthreads();
        const int e0 = b * EPB;
        const int eend = min(e0 + EPB, N_EDGES);
        for (int e = e0 + tid; e < eend; e += 512) {
            int d = dst[e];
            int old = atomicAdd(&cnt[d >> 1], (d & 1) ? (1 << 16) : 1);
            erank[e] = (d & 1) ? ((old >> 16) & 0xffff) : (old & 0xffff);
        }
        __syncthreads();
        int* hb = hist + (size_t)b * N_NODES;
        for (int i = tid; i < N_NODES / 2; i += 512) {
            int v = cnt[i];
            int2 o; o.x = v & 0xffff; o.y = ((unsigned)v) >> 16;
            *(int2*)(hb + 2 * i) = o;
        }
        return;
    }

    // -------- GEMM block (BM=256) --------
    const int m0 = (blockIdx.x - NHB) * 256;

    #pragma unroll
    for (int c = 0; c < 16; c++) {
        int o = c * 8192 + tid * 16;            // byte offset
        bf16x8 v = *(const bf16x8*)((const char*)Bt + o);
        int nl = o >> 9;
        int lb = o ^ ((nl & 7) << 4);
        *(bf16x8*)(smem + lb) = v;
    }
    __syncthreads();

    const int w = tid >> 6, lane = tid & 63;
    const int wm = w >> 2, wn = w & 3;          // 2 x 4; wave: 128 rows x 64 cols (head wn)
    const int fr = lane & 15, quad = lane >> 4;

    const float* arow[8];
    int gm[8];
    #pragma unroll
    for (int j = 0; j < 8; j++) {
        gm[j] = m0 + wm * 128 + j * 16 + fr;
        int cr = gm[j] < M ? gm[j] : (M - 1);
        arow[j] = A + (size_t)cr * IN_F;
    }

    f32x4 acc[8][4];
    #pragma unroll
    for (int j = 0; j < 8; j++)
        #pragma unroll
        for (int f = 0; f < 4; f++) acc[j][f] = (f32x4){0.f, 0.f, 0.f, 0.f};

    #pragma unroll
    for (int kk = 0; kk < 8; kk++) {
        bf16x8 af[8];
        #pragma unroll
        for (int j = 0; j < 8; j++) {
            float4 lo = *(const float4*)(arow[j] + kk * 32 + quad * 8);
            float4 hi = *(const float4*)(arow[j] + kk * 32 + quad * 8 + 4);
            af[j][0] = (short)f2bf(lo.x); af[j][1] = (short)f2bf(lo.y);
            af[j][2] = (short)f2bf(lo.z); af[j][3] = (short)f2bf(lo.w);
            af[j][4] = (short)f2bf(hi.x); af[j][5] = (short)f2bf(hi.y);
            af[j][6] = (short)f2bf(hi.z); af[j][7] = (short)f2bf(hi.w);
        }
        #pragma unroll
        for (int f = 0; f < 4; f++) {
            int nl = wn * 64 + f * 16 + fr;
            int lb = (nl * 512 + (kk * 32 + quad * 8) * 2) ^ ((nl & 7) << 4);
            bf16x8 bfr = *(const bf16x8*)(smem + lb);
            #pragma unroll
            for (int j = 0; j < 8; j++)
                acc[j][f] = __builtin_amdgcn_mfma_f32_16x16x32_bf16(bfr, af[j], acc[j][f], 0, 0, 0);
        }
    }
    // lane holds D[row = m0+wm*128+j*16+fr][col = wn*64+f*16+quad*4+r]

    // fused el/er (head wn)
    #pragma unroll
    for (int j = 0; j < 8; j++) {
        float pl = 0.f, pr = 0.f;
        #pragma unroll
        for (int f = 0; f < 4; f++) {
            float4 a4 = *(const float4*)(al + wn * 64 + f * 16 + quad * 4);
            float4 b4 = *(const float4*)(ar + wn * 64 + f * 16 + quad * 4);
            pl += acc[j][f][0] * a4.x + acc[j][f][1] * a4.y + acc[j][f][2] * a4.z + acc[j][f][3] * a4.w;
            pr += acc[j][f][0] * b4.x + acc[j][f][1] * b4.y + acc[j][f][2] * b4.z + acc[j][f][3] * b4.w;
        }
        pl += __shfl_xor(pl, 16); pl += __shfl_xor(pl, 32);
        pr += __shfl_xor(pr, 16); pr += __shfl_xor(pr, 32);
        if (quad == 0 && gm[j] < M) {
            el[gm[j] * NH + wn] = pl;
            er[gm[j] * NH + wn] = pr;
        }
    }

    // direct f16 stores
    #pragma unroll
    for (int j = 0; j < 8; j++) {
        if (gm[j] < M) {
            unsigned short* dp = fth + (size_t)gm[j] * HD + wn * 64 + quad * 4;
            #pragma unroll
            for (int f = 0; f < 4; f++) {
                ushort4 pk;
                pk.x = __half_as_ushort(__float2half(acc[j][f][0]));
                pk.y = __half_as_ushort(__float2half(acc[j][f][1]));
                pk.z = __half_as_ushort(__float2half(acc[j][f][2]));
                pk.w = __half_as_ushort(__float2half(acc[j][f][3]));
                *(ushort4*)(dp + f * 16) = pk;
            }
        }
    }
}

// ---------------- CSR scan: merge NHB copies -> counts, per-copy exclusive prefix ----
__global__ __launch_bounds__(512) void k_scan1(int* __restrict__ hist,
                                               int* __restrict__ counts,
                                               int* __restrict__ incl,
                                               int* __restrict__ bsum, int N) {
    __shared__ int sm[512];
    int i = blockIdx.x * 512 + threadIdx.x;
    int v = 0;
    if (i < N) {
        int pf = 0;
        for (int c = 0; c < NHB; c++) {
            int t = hist[(size_t)c * N_NODES + i];
            hist[(size_t)c * N_NODES + i] = pf;  // exclusive prefix over copies
            pf += t;
        }
        v = pf;
        counts[i] = v;
    }
    sm[threadIdx.x] = v;
    __syncthreads();
    for (int off = 1; off < 512; off <<= 1) {
        int t = (threadIdx.x >= off) ? sm[threadIdx.x - off] : 0;
        __syncthreads();
        sm[threadIdx.x] += t;
        __syncthreads();
    }
    if (i < N) incl[i] = sm[threadIdx.x];
    if (threadIdx.x == 511) bsum[blockIdx.x] = sm[511];
}

// scan3: offs only (no fold; scatter gathers offs[d] separately, L2-hot)
__global__ __launch_bounds__(256) void k_scan3(const int* __restrict__ counts,
                                               const int* __restrict__ incl,
                                               const int* __restrict__ bsum,
                                               int* __restrict__ offs, int N) {
    __shared__ int sprefix;
    int nb = blockIdx.x >> 1;
    if (threadIdx.x < 64) {
        int v = 0;
        for (int j = threadIdx.x; j < nb; j += 64) v += bsum[j];
        #pragma unroll
        for (int off = 1; off < 64; off <<= 1) v += __shfl_xor(v, off);
        if (threadIdx.x == 0) sprefix = v;
    }
    __syncthreads();
    int i = blockIdx.x * 256 + threadIdx.x;
    if (i < N) offs[i] = incl[i] - counts[i] + sprefix;
}

// ---------------- scatter: atomic-free, two L2-hot gathers ----------------
__global__ __launch_bounds__(256) void k_scatter(const int* __restrict__ src,
                                                 const int* __restrict__ dst,
                                                 const int* __restrict__ hist,
                                                 const int* __restrict__ offs,
                                                 const int* __restrict__ erank,
                                                 int* __restrict__ esrc) {
    int e = blockIdx.x * 256 + threadIdx.x;
    if (e < N_EDGES) {
        int d = dst[e];
        int c = e >> 14;                         // same block mapping as hist
        int p = hist[(size_t)c * N_NODES + d] + offs[d] + erank[e];
        esrc[p] = src[e];
    }
}

// ---------------- Aggregation: one wave per dst node, SINGLE PASS ----------------
__global__ __launch_bounds__(256) void k_agg(const unsigned short* __restrict__ fth,
                                             const float* __restrict__ el,
                                             const float* __restrict__ er,
                                             const int* __restrict__ offs,
                                             const int* __restrict__ counts,
                                             const int* __restrict__ esrc,
                                             float* __restrict__ out, int N) {
    int wid = (blockIdx.x * 256 + threadIdx.x) >> 6;
    const int lane = threadIdx.x & 63;
    if (wid >= N) return;
    const int deg = counts[wid];
    const int start = offs[wid];
    const int quad = lane >> 4;                 // head of my 4 cols
    const float erq = er[wid * NH + quad];

    float s = 0.f;
    float a0 = 0.f, a1 = 0.f, a2 = 0.f, a3 = 0.f;
    #pragma unroll 4
    for (int i = 0; i < deg; i++) {
        int sv = esrc[start + i];                     // wave-uniform
        float x = el[sv * NH + quad] + erq;           // 1-line broadcast gather
        x = (x > 0.f) ? x : ALPHA * x;
        float wgt = __expf(x);
        s += wgt;
        float2 raw = ((const float2*)fth)[(size_t)sv * 64 + lane];
        __half2 h0 = *reinterpret_cast<const __half2*>(&raw.x);
        __half2 h1 = *reinterpret_cast<const __half2*>(&raw.y);
        a0 = fmaf(wgt, __low2float(h0), a0);
        a1 = fmaf(wgt, __high2float(h0), a1);
        a2 = fmaf(wgt, __low2float(h1), a2);
        a3 = fmaf(wgt, __high2float(h1), a3);
    }
    float invd = (deg > 0 && s > 0.f) ? 1.f / s : 0.f;
    f32x4 o;
    o[0] = a0 * invd; o[1] = a1 * invd; o[2] = a2 * invd; o[3] = a3 * invd;
    __builtin_nontemporal_store(o, (f32x4*)out + (size_t)wid * 64 + lane);
}

// ---------------- launch ----------------
extern "C" void kernel_launch(void* const* d_in, const int* in_sizes, int n_in,
                              void* d_out, int out_size, void* d_ws, size_t ws_size,
                              hipStream_t stream) {
    const float* feat = (const float*)d_in[0];
    const float* fc_w = (const float*)d_in[1];
    const float* attn_l = (const float*)d_in[2];
    const float* attn_r = (const float*)d_in[3];
    const int* src = (const int*)d_in[4];
    const int* dst = (const int*)d_in[5];
    float* out = (float*)d_out;

    char* w = (char*)d_ws;
    unsigned short* fth = (unsigned short*)w;  w += (size_t)N_NODES * HD * 2;      // 25.6 MB (f16)
    unsigned short* Bt = (unsigned short*)w;   w += (size_t)IN_F * HD * 2;         // 128 KB (bf16)
    float* el = (float*)w;       w += (size_t)N_NODES * NH * 4;                    // 800 KB
    float* er = (float*)w;       w += (size_t)N_NODES * NH * 4;                    // 800 KB
    int* hist = (int*)w;         w += (size_t)NHB * N_NODES * 4;                   // 9.8 MB
    int* counts = (int*)w;       w += (size_t)N_NODES * 4;
    int* incl = (int*)w;         w += (size_t)N_NODES * 4;
    int* offs = (int*)w;         w += (size_t)N_NODES * 4;
    int* bsum = (int*)w;         w += 1024;
    int* erank = (int*)w;        w += (size_t)N_EDGES * 4;                          // 3.2 MB
    int* esrc = (int*)w;         w += (size_t)N_EDGES * 4;                          // 3.2 MB

    k_cvt<<<256, 256, 0, stream>>>(fc_w, Bt);

    // main: 49 hist blocks + 196 gemm blocks, one dispatch, one scheduling round
    k_main<<<NHB + GEMMB, 512, 0, stream>>>(feat, Bt, fth, el, er, attn_l, attn_r,
                                            dst, hist, erank, N_NODES);

    int nsb = (N_NODES + 511) / 512;
    k_scan1<<<nsb, 512, 0, stream>>>(hist, counts, incl, bsum, N_NODES);
    k_scan3<<<(N_NODES + 255) / 256, 256, 0, stream>>>(counts, incl, bsum, offs, N_NODES);

    int eblocks = (N_EDGES + 255) / 256;
    k_scatter<<<eblocks, 256, 0, stream>>>(src, dst, hist, offs, erank, esrc);

    int agg_blocks = (N_NODES * 64 + 255) / 256;
    k_agg<<<agg_blocks, 256, 0, stream>>>(fth, el, er, offs, counts, esrc, out, N_NODES);
}

// Round 21
// 142.850 us; speedup vs baseline: 1.1574x; 1.0199x over previous
//
#include <hip/hip_runtime.h>
#include <hip/hip_bf16.h>
#include <hip/hip_fp16.h>

#define N_NODES 50000
#define N_EDGES 800000
#define IN_F 256
#define NH 4
#define DH 64
#define HD 256
#define ALPHA 0.2f
#define EPB 16384                                  // edges per hist block (2^14)
#define NHB ((N_EDGES + EPB - 1) / EPB)            // 49 hist blocks / copies
#define GEMMB ((N_NODES + 255) / 256)              // 196 gemm blocks (BM=256)

typedef short bf16x8 __attribute__((ext_vector_type(8)));
typedef float f32x4 __attribute__((ext_vector_type(4)));

__device__ __forceinline__ unsigned short f2bf(float f) {
    unsigned u = __float_as_uint(f);
    u = (u + 0x7FFFu + ((u >> 16) & 1u)) >> 16;   // RNE
    return (unsigned short)u;
}

// ---------------- cvt: Bt transpose-convert + zero the segment cursor ----------
__global__ __launch_bounds__(256) void k_cvt(const float* __restrict__ fw,
                                             unsigned short* __restrict__ Bt,
                                             int* __restrict__ gcursor) {
    if (blockIdx.x == 0 && threadIdx.x == 0) *gcursor = 0;
    int n = blockIdx.x;            // 0..255
    int k = threadIdx.x;           // 0..255
    Bt[n * 256 + k] = f2bf(fw[k * 256 + n]);
}

// ---------------- MAIN: blocks 0..48 = LDS-hist, blocks 49.. = GEMM tile --------
// HIST: block b owns edges [b*EPB, b*EPB+EPB); full node histogram in LDS as
// packed 2xu16 (100 KB). LDS atomicAdd returns rank -> erank16[e] (u16); the
// packed cnt array IS the u16 hist layout -> raw int4 dump, no unpack.
// GEMM: BM=256, BN=256 (full), 512 thr = 8 waves (2M x 4N, 128 rows/wave);
// B staged once in LDS (XOR-swizzled, 128 KB). 196+49 = 245 blocks = one round.
__global__ __launch_bounds__(512) void k_main(const float* __restrict__ A,
                                              const unsigned short* __restrict__ Bt,
                                              unsigned short* __restrict__ fth,
                                              float* __restrict__ el,
                                              float* __restrict__ er,
                                              const float* __restrict__ al,
                                              const float* __restrict__ ar,
                                              const int* __restrict__ dst,
                                              unsigned short* __restrict__ hist16,
                                              unsigned short* __restrict__ erank16, int M) {
    __shared__ __align__(16) char smem[131072];
    const int tid = threadIdx.x;

    if (blockIdx.x < NHB) {
        // -------- histogram block (LDS counting, packed 2xu16) --------
        int* cnt = (int*)smem;                     // 100 KB used
        const int b = blockIdx.x;
        for (int i = tid; i < N_NODES / 2; i += 512) cnt[i] = 0;
        __syncthreads();
        const int e0 = b * EPB;
        const int eend = min(e0 + EPB, N_EDGES);
        for (int e = e0 + tid; e < eend; e += 512) {
            int d = dst[e];
            int old = atomicAdd(&cnt[d >> 1], (d & 1) ? (1 << 16) : 1);
            erank16[e] = (unsigned short)((d & 1) ? ((old >> 16) & 0xffff) : (old & 0xffff));
        }
        __syncthreads();
        // raw dump: cnt's packed 2xu16 layout == hist16[b][node]
        int4* hb = (int4*)(hist16 + (size_t)b * N_NODES);
        for (int i = tid; i < N_NODES / 8; i += 512)
            hb[i] = ((const int4*)cnt)[i];
        return;
    }

    // -------- GEMM block (BM=256) --------
    const int m0 = (blockIdx.x - NHB) * 256;

    #pragma unroll
    for (int c = 0; c < 16; c++) {
        int o = c * 8192 + tid * 16;            // byte offset
        bf16x8 v = *(const bf16x8*)((const char*)Bt + o);
        int nl = o >> 9;
        int lb = o ^ ((nl & 7) << 4);
        *(bf16x8*)(smem + lb) = v;
    }
    __syncthreads();

    const int w = tid >> 6, lane = tid & 63;
    const int wm = w >> 2, wn = w & 3;          // 2 x 4; wave: 128 rows x 64 cols (head wn)
    const int fr = lane & 15, quad = lane >> 4;

    const float* arow[8];
    int gm[8];
    #pragma unroll
    for (int j = 0; j < 8; j++) {
        gm[j] = m0 + wm * 128 + j * 16 + fr;
        int cr = gm[j] < M ? gm[j] : (M - 1);
        arow[j] = A + (size_t)cr * IN_F;
    }

    f32x4 acc[8][4];
    #pragma unroll
    for (int j = 0; j < 8; j++)
        #pragma unroll
        for (int f = 0; f < 4; f++) acc[j][f] = (f32x4){0.f, 0.f, 0.f, 0.f};

    #pragma unroll
    for (int kk = 0; kk < 8; kk++) {
        bf16x8 af[8];
        #pragma unroll
        for (int j = 0; j < 8; j++) {
            float4 lo = *(const float4*)(arow[j] + kk * 32 + quad * 8);
            float4 hi = *(const float4*)(arow[j] + kk * 32 + quad * 8 + 4);
            af[j][0] = (short)f2bf(lo.x); af[j][1] = (short)f2bf(lo.y);
            af[j][2] = (short)f2bf(lo.z); af[j][3] = (short)f2bf(lo.w);
            af[j][4] = (short)f2bf(hi.x); af[j][5] = (short)f2bf(hi.y);
            af[j][6] = (short)f2bf(hi.z); af[j][7] = (short)f2bf(hi.w);
        }
        #pragma unroll
        for (int f = 0; f < 4; f++) {
            int nl = wn * 64 + f * 16 + fr;
            int lb = (nl * 512 + (kk * 32 + quad * 8) * 2) ^ ((nl & 7) << 4);
            bf16x8 bfr = *(const bf16x8*)(smem + lb);
            #pragma unroll
            for (int j = 0; j < 8; j++)
                acc[j][f] = __builtin_amdgcn_mfma_f32_16x16x32_bf16(bfr, af[j], acc[j][f], 0, 0, 0);
        }
    }
    // lane holds D[row = m0+wm*128+j*16+fr][col = wn*64+f*16+quad*4+r]

    // fused el/er (head wn)
    #pragma unroll
    for (int j = 0; j < 8; j++) {
        float pl = 0.f, pr = 0.f;
        #pragma unroll
        for (int f = 0; f < 4; f++) {
            float4 a4 = *(const float4*)(al + wn * 64 + f * 16 + quad * 4);
            float4 b4 = *(const float4*)(ar + wn * 64 + f * 16 + quad * 4);
            pl += acc[j][f][0] * a4.x + acc[j][f][1] * a4.y + acc[j][f][2] * a4.z + acc[j][f][3] * a4.w;
            pr += acc[j][f][0] * b4.x + acc[j][f][1] * b4.y + acc[j][f][2] * b4.z + acc[j][f][3] * b4.w;
        }
        pl += __shfl_xor(pl, 16); pl += __shfl_xor(pl, 32);
        pr += __shfl_xor(pr, 16); pr += __shfl_xor(pr, 32);
        if (quad == 0 && gm[j] < M) {
            el[gm[j] * NH + wn] = pl;
            er[gm[j] * NH + wn] = pr;
        }
    }

    // direct f16 stores
    #pragma unroll
    for (int j = 0; j < 8; j++) {
        if (gm[j] < M) {
            unsigned short* dp = fth + (size_t)gm[j] * HD + wn * 64 + quad * 4;
            #pragma unroll
            for (int f = 0; f < 4; f++) {
                ushort4 pk;
                pk.x = __half_as_ushort(__float2half(acc[j][f][0]));
                pk.y = __half_as_ushort(__float2half(acc[j][f][1]));
                pk.z = __half_as_ushort(__float2half(acc[j][f][2]));
                pk.w = __half_as_ushort(__float2half(acc[j][f][3]));
                *(ushort4*)(dp + f * 16) = pk;
            }
        }
    }
}

// ---------------- fused scan: per-copy u16 prefixes + unordered segment alloc ----
// hist16[c][i] -> exclusive prefix over copies (u16, fits: <= deg(i) < 2^16).
// Block-local prefix of node totals; block base from one atomicAdd on gcursor.
// offs order across blocks is arbitrary -> within-node edge order unchanged ->
// output bitwise deterministic.
__global__ __launch_bounds__(512) void k_scan(unsigned short* __restrict__ hist16,
                                              int* __restrict__ counts,
                                              int* __restrict__ offs,
                                              int* __restrict__ gcursor, int N) {
    __shared__ int sm[512];
    __shared__ int sbase;
    int i = blockIdx.x * 512 + threadIdx.x;
    int v = 0;
    if (i < N) {
        int pf = 0;
        for (int c = 0; c < NHB; c++) {
            unsigned short* p = hist16 + (size_t)c * N_NODES + i;
            int t = *p;
            *p = (unsigned short)pf;
            pf += t;
        }
        v = pf;
        counts[i] = v;
    }
    sm[threadIdx.x] = v;
    __syncthreads();
    for (int off = 1; off < 512; off <<= 1) {
        int t = (threadIdx.x >= off) ? sm[threadIdx.x - off] : 0;
        __syncthreads();
        sm[threadIdx.x] += t;
        __syncthreads();
    }
    if (threadIdx.x == 511) sbase = atomicAdd(gcursor, sm[511]);
    __syncthreads();
    if (i < N) offs[i] = sbase + sm[threadIdx.x] - v;
}

// ---------------- scatter: atomic-free, 4 edges/thread, vectorized ----------------
__global__ __launch_bounds__(256) void k_scatter(const int* __restrict__ src,
                                                 const int* __restrict__ dst,
                                                 const unsigned short* __restrict__ hist16,
                                                 const int* __restrict__ offs,
                                                 const unsigned short* __restrict__ erank16,
                                                 int* __restrict__ esrc) {
    int t = blockIdx.x * 256 + threadIdx.x;
    if (t >= N_EDGES / 4) return;
    int e = t * 4;
    const unsigned short* hp = hist16 + (size_t)(e >> 14) * N_NODES;  // same c for all 4
    int4 d4 = *(const int4*)(dst + e);
    int4 s4 = *(const int4*)(src + e);
    ushort4 r4 = *(const ushort4*)(erank16 + e);
    esrc[hp[d4.x] + offs[d4.x] + r4.x] = s4.x;
    esrc[hp[d4.y] + offs[d4.y] + r4.y] = s4.y;
    esrc[hp[d4.z] + offs[d4.z] + r4.z] = s4.z;
    esrc[hp[d4.w] + offs[d4.w] + r4.w] = s4.w;
}

// ---------------- Aggregation: one wave per dst node, SINGLE PASS ----------------
__global__ __launch_bounds__(256) void k_agg(const unsigned short* __restrict__ fth,
                                             const float* __restrict__ el,
                                             const float* __restrict__ er,
                                             const int* __restrict__ offs,
                                             const int* __restrict__ counts,
                                             const int* __restrict__ esrc,
                                             float* __restrict__ out, int N) {
    int wid = (blockIdx.x * 256 + threadIdx.x) >> 6;
    const int lane = threadIdx.x & 63;
    if (wid >= N) return;
    const int deg = counts[wid];
    const int start = offs[wid];
    const int quad = lane >> 4;                 // head of my 4 cols
    const float erq = er[wid * NH + quad];

    float s = 0.f;
    float a0 = 0.f, a1 = 0.f, a2 = 0.f, a3 = 0.f;
    #pragma unroll 4
    for (int i = 0; i < deg; i++) {
        int sv = esrc[start + i];                     // wave-uniform
        float x = el[sv * NH + quad] + erq;           // 1-line broadcast gather
        x = (x > 0.f) ? x : ALPHA * x;
        float wgt = __expf(x);
        s += wgt;
        float2 raw = ((const float2*)fth)[(size_t)sv * 64 + lane];
        __half2 h0 = *reinterpret_cast<const __half2*>(&raw.x);
        __half2 h1 = *reinterpret_cast<const __half2*>(&raw.y);
        a0 = fmaf(wgt, __low2float(h0), a0);
        a1 = fmaf(wgt, __high2float(h0), a1);
        a2 = fmaf(wgt, __low2float(h1), a2);
        a3 = fmaf(wgt, __high2float(h1), a3);
    }
    float invd = (deg > 0 && s > 0.f) ? 1.f / s : 0.f;
    f32x4 o;
    o[0] = a0 * invd; o[1] = a1 * invd; o[2] = a2 * invd; o[3] = a3 * invd;
    __builtin_nontemporal_store(o, (f32x4*)out + (size_t)wid * 64 + lane);
}

// ---------------- launch ----------------
extern "C" void kernel_launch(void* const* d_in, const int* in_sizes, int n_in,
                              void* d_out, int out_size, void* d_ws, size_t ws_size,
                              hipStream_t stream) {
    const float* feat = (const float*)d_in[0];
    const float* fc_w = (const float*)d_in[1];
    const float* attn_l = (const float*)d_in[2];
    const float* attn_r = (const float*)d_in[3];
    const int* src = (const int*)d_in[4];
    const int* dst = (const int*)d_in[5];
    float* out = (float*)d_out;

    char* w = (char*)d_ws;
    unsigned short* fth = (unsigned short*)w;  w += (size_t)N_NODES * HD * 2;      // 25.6 MB (f16)
    unsigned short* Bt = (unsigned short*)w;   w += (size_t)IN_F * HD * 2;         // 128 KB (bf16)
    float* el = (float*)w;       w += (size_t)N_NODES * NH * 4;                    // 800 KB
    float* er = (float*)w;       w += (size_t)N_NODES * NH * 4;                    // 800 KB
    unsigned short* hist16 = (unsigned short*)w;  w += (size_t)NHB * N_NODES * 2;  // 4.9 MB
    int* counts = (int*)w;       w += (size_t)N_NODES * 4;
    int* offs = (int*)w;         w += (size_t)N_NODES * 4;
    int* gcursor = (int*)w;      w += 256;
    unsigned short* erank16 = (unsigned short*)w; w += (size_t)N_EDGES * 2;        // 1.6 MB
    int* esrc = (int*)w;         w += (size_t)N_EDGES * 4;                          // 3.2 MB

    k_cvt<<<256, 256, 0, stream>>>(fc_w, Bt, gcursor);

    // main: 49 hist blocks + 196 gemm blocks, one dispatch, one scheduling round
    k_main<<<NHB + GEMMB, 512, 0, stream>>>(feat, Bt, fth, el, er, attn_l, attn_r,
                                            dst, hist16, erank16, N_NODES);

    k_scan<<<(N_NODES + 511) / 512, 512, 0, stream>>>(hist16, counts, offs,
                                                      gcursor, N_NODES);

    k_scatter<<<(N_EDGES / 4 + 255) / 256, 256, 0, stream>>>(src, dst, hist16,
                                                             offs, erank16, esrc);

    int agg_blocks = (N_NODES * 64 + 255) / 256;
    k_agg<<<agg_blocks, 256, 0, stream>>>(fth, el, er, offs, counts, esrc, out, N_NODES);
}

// Round 22
// 142.586 us; speedup vs baseline: 1.1595x; 1.0019x over previous
//
#include <hip/hip_runtime.h>
#include <hip/hip_bf16.h>
#include <hip/hip_fp16.h>

#define N_NODES 50000
#define N_EDGES 800000
#define IN_F 256
#define NH 4
#define DH 64
#define HD 256
#define ALPHA 0.2f
#define EPB 16384                                  // edges per hist block (2^14)
#define NHB ((N_EDGES + EPB - 1) / EPB)            // 49 hist blocks / copies
#define GEMMB ((N_NODES + 255) / 256)              // 196 gemm blocks (BM=256)
#define SCATB ((N_EDGES / 8 + 511) / 512)          // 196 scatter blocks

typedef short bf16x8 __attribute__((ext_vector_type(8)));
typedef float f32x4 __attribute__((ext_vector_type(4)));

__device__ __forceinline__ unsigned short f2bf(float f) {
    unsigned u = __float_as_uint(f);
    u = (u + 0x7FFFu + ((u >> 16) & 1u)) >> 16;   // RNE
    return (unsigned short)u;
}

// ---------------- PRE: blocks 0..48 = LDS-hist, blocks 49..176 = Bt cvt ----------
// HIST: block b owns edges [b*EPB, b*EPB+EPB); full node histogram in LDS as
// packed 2xu16 (100 KB). LDS atomicAdd returns rank -> erank16[e]; packed cnt
// array IS the u16 hist layout -> raw int4 dump.
// CVT: Bt[n][k] = bf16(fw[k][n]); also resets gcursor.
__global__ __launch_bounds__(512) void k_pre(const float* __restrict__ fw,
                                             unsigned short* __restrict__ Bt,
                                             const int* __restrict__ dst,
                                             unsigned short* __restrict__ hist16,
                                             unsigned short* __restrict__ erank16,
                                             int* __restrict__ gcursor) {
    __shared__ int cnt[N_NODES / 2];               // 100 KB
    const int tid = threadIdx.x;

    if (blockIdx.x >= NHB) {
        if (blockIdx.x == NHB && tid == 0) *gcursor = 0;
        int t = (blockIdx.x - NHB) * 512 + tid;    // 0..65535
        int n = t >> 8, k = t & 255;
        Bt[n * 256 + k] = f2bf(fw[k * 256 + n]);
        return;
    }

    const int b = blockIdx.x;
    for (int i = tid; i < N_NODES / 2; i += 512) cnt[i] = 0;
    __syncthreads();
    const int e0 = b * EPB;
    const int eend = min(e0 + EPB, N_EDGES);
    for (int e = e0 + tid; e < eend; e += 512) {
        int d = dst[e];
        int old = atomicAdd(&cnt[d >> 1], (d & 1) ? (1 << 16) : 1);
        erank16[e] = (unsigned short)((d & 1) ? ((old >> 16) & 0xffff) : (old & 0xffff));
    }
    __syncthreads();
    int4* hb = (int4*)(hist16 + (size_t)b * N_NODES);
    for (int i = tid; i < N_NODES / 8; i += 512)
        hb[i] = ((const int4*)cnt)[i];
}

// ---------------- fused scan: per-copy u16 prefixes + unordered segment alloc ----
__global__ __launch_bounds__(512) void k_scan(unsigned short* __restrict__ hist16,
                                              int* __restrict__ counts,
                                              int* __restrict__ offs,
                                              int* __restrict__ gcursor, int N) {
    __shared__ int sm[512];
    __shared__ int sbase;
    int i = blockIdx.x * 512 + threadIdx.x;
    int v = 0;
    if (i < N) {
        int pf = 0;
        for (int c = 0; c < NHB; c++) {
            unsigned short* p = hist16 + (size_t)c * N_NODES + i;
            int t = *p;
            *p = (unsigned short)pf;
            pf += t;
        }
        v = pf;
        counts[i] = v;
    }
    sm[threadIdx.x] = v;
    __syncthreads();
    for (int off = 1; off < 512; off <<= 1) {
        int t = (threadIdx.x >= off) ? sm[threadIdx.x - off] : 0;
        __syncthreads();
        sm[threadIdx.x] += t;
        __syncthreads();
    }
    if (threadIdx.x == 511) sbase = atomicAdd(gcursor, sm[511]);
    __syncthreads();
    if (i < N) offs[i] = sbase + sm[threadIdx.x] - v;
}

// ---------------- MAIN: blocks 0..195 = GEMM (BM=256), blocks 196.. = scatter ----
// GEMM: BM=256, BN=256 (full), 512 thr = 8 waves (2M x 4N, 128 rows/wave);
// B staged once in LDS (XOR-swizzled, 128 KB). Swapped-operand MFMA -> direct
// packed f16 stores + in-register el/er.
// SCATTER: 8 edges/thread, vectorized, atomic-free; hides under gemm.
__global__ __launch_bounds__(512) void k_main(const float* __restrict__ A,
                                              const unsigned short* __restrict__ Bt,
                                              unsigned short* __restrict__ fth,
                                              float* __restrict__ el,
                                              float* __restrict__ er,
                                              const float* __restrict__ al,
                                              const float* __restrict__ ar,
                                              const int* __restrict__ src,
                                              const int* __restrict__ dst,
                                              const unsigned short* __restrict__ hist16,
                                              const int* __restrict__ offs,
                                              const unsigned short* __restrict__ erank16,
                                              int* __restrict__ esrc, int M) {
    __shared__ __align__(16) char smem[131072];
    const int tid = threadIdx.x;

    if (blockIdx.x >= GEMMB) {
        // -------- scatter block: 8 edges/thread --------
        int t = (blockIdx.x - GEMMB) * 512 + tid;
        if (t < N_EDGES / 8) {
            int e = t * 8;
            const unsigned short* hp = hist16 + (size_t)(e >> 14) * N_NODES;
            int4 da = *(const int4*)(dst + e);
            int4 db = *(const int4*)(dst + e + 4);
            int4 sa = *(const int4*)(src + e);
            int4 sb = *(const int4*)(src + e + 4);
            ushort4 ra = *(const ushort4*)(erank16 + e);
            ushort4 rb = *(const ushort4*)(erank16 + e + 4);
            esrc[hp[da.x] + offs[da.x] + ra.x] = sa.x;
            esrc[hp[da.y] + offs[da.y] + ra.y] = sa.y;
            esrc[hp[da.z] + offs[da.z] + ra.z] = sa.z;
            esrc[hp[da.w] + offs[da.w] + ra.w] = sa.w;
            esrc[hp[db.x] + offs[db.x] + rb.x] = sb.x;
            esrc[hp[db.y] + offs[db.y] + rb.y] = sb.y;
            esrc[hp[db.z] + offs[db.z] + rb.z] = sb.z;
            esrc[hp[db.w] + offs[db.w] + rb.w] = sb.w;
        }
        return;
    }

    // -------- GEMM block (BM=256) --------
    const int m0 = blockIdx.x * 256;

    #pragma unroll
    for (int c = 0; c < 16; c++) {
        int o = c * 8192 + tid * 16;            // byte offset
        bf16x8 v = *(const bf16x8*)((const char*)Bt + o);
        int nl = o >> 9;
        int lb = o ^ ((nl & 7) << 4);
        *(bf16x8*)(smem + lb) = v;
    }
    __syncthreads();

    const int w = tid >> 6, lane = tid & 63;
    const int wm = w >> 2, wn = w & 3;          // 2 x 4; wave: 128 rows x 64 cols (head wn)
    const int fr = lane & 15, quad = lane >> 4;

    const float* arow[8];
    int gm[8];
    #pragma unroll
    for (int j = 0; j < 8; j++) {
        gm[j] = m0 + wm * 128 + j * 16 + fr;
        int cr = gm[j] < M ? gm[j] : (M - 1);
        arow[j] = A + (size_t)cr * IN_F;
    }

    f32x4 acc[8][4];
    #pragma unroll
    for (int j = 0; j < 8; j++)
        #pragma unroll
        for (int f = 0; f < 4; f++) acc[j][f] = (f32x4){0.f, 0.f, 0.f, 0.f};

    #pragma unroll
    for (int kk = 0; kk < 8; kk++) {
        bf16x8 af[8];
        #pragma unroll
        for (int j = 0; j < 8; j++) {
            float4 lo = *(const float4*)(arow[j] + kk * 32 + quad * 8);
            float4 hi = *(const float4*)(arow[j] + kk * 32 + quad * 8 + 4);
            af[j][0] = (short)f2bf(lo.x); af[j][1] = (short)f2bf(lo.y);
            af[j][2] = (short)f2bf(lo.z); af[j][3] = (short)f2bf(lo.w);
            af[j][4] = (short)f2bf(hi.x); af[j][5] = (short)f2bf(hi.y);
            af[j][6] = (short)f2bf(hi.z); af[j][7] = (short)f2bf(hi.w);
        }
        #pragma unroll
        for (int f = 0; f < 4; f++) {
            int nl = wn * 64 + f * 16 + fr;
            int lb = (nl * 512 + (kk * 32 + quad * 8) * 2) ^ ((nl & 7) << 4);
            bf16x8 bfr = *(const bf16x8*)(smem + lb);
            #pragma unroll
            for (int j = 0; j < 8; j++)
                acc[j][f] = __builtin_amdgcn_mfma_f32_16x16x32_bf16(bfr, af[j], acc[j][f], 0, 0, 0);
        }
    }
    // lane holds D[row = m0+wm*128+j*16+fr][col = wn*64+f*16+quad*4+r]

    // fused el/er (head wn)
    #pragma unroll
    for (int j = 0; j < 8; j++) {
        float pl = 0.f, pr = 0.f;
        #pragma unroll
        for (int f = 0; f < 4; f++) {
            float4 a4 = *(const float4*)(al + wn * 64 + f * 16 + quad * 4);
            float4 b4 = *(const float4*)(ar + wn * 64 + f * 16 + quad * 4);
            pl += acc[j][f][0] * a4.x + acc[j][f][1] * a4.y + acc[j][f][2] * a4.z + acc[j][f][3] * a4.w;
            pr += acc[j][f][0] * b4.x + acc[j][f][1] * b4.y + acc[j][f][2] * b4.z + acc[j][f][3] * b4.w;
        }
        pl += __shfl_xor(pl, 16); pl += __shfl_xor(pl, 32);
        pr += __shfl_xor(pr, 16); pr += __shfl_xor(pr, 32);
        if (quad == 0 && gm[j] < M) {
            el[gm[j] * NH + wn] = pl;
            er[gm[j] * NH + wn] = pr;
        }
    }

    // direct f16 stores
    #pragma unroll
    for (int j = 0; j < 8; j++) {
        if (gm[j] < M) {
            unsigned short* dp = fth + (size_t)gm[j] * HD + wn * 64 + quad * 4;
            #pragma unroll
            for (int f = 0; f < 4; f++) {
                ushort4 pk;
                pk.x = __half_as_ushort(__float2half(acc[j][f][0]));
                pk.y = __half_as_ushort(__float2half(acc[j][f][1]));
                pk.z = __half_as_ushort(__float2half(acc[j][f][2]));
                pk.w = __half_as_ushort(__float2half(acc[j][f][3]));
                *(ushort4*)(dp + f * 16) = pk;
            }
        }
    }
}

// ---------------- Aggregation: one wave per dst node, SINGLE PASS ----------------
__global__ __launch_bounds__(256) void k_agg(const unsigned short* __restrict__ fth,
                                             const float* __restrict__ el,
                                             const float* __restrict__ er,
                                             const int* __restrict__ offs,
                                             const int* __restrict__ counts,
                                             const int* __restrict__ esrc,
                                             float* __restrict__ out, int N) {
    int wid = (blockIdx.x * 256 + threadIdx.x) >> 6;
    const int lane = threadIdx.x & 63;
    if (wid >= N) return;
    const int deg = counts[wid];
    const int start = offs[wid];
    const int quad = lane >> 4;                 // head of my 4 cols
    const float erq = er[wid * NH + quad];

    float s = 0.f;
    float a0 = 0.f, a1 = 0.f, a2 = 0.f, a3 = 0.f;
    #pragma unroll 4
    for (int i = 0; i < deg; i++) {
        int sv = esrc[start + i];                     // wave-uniform
        float x = el[sv * NH + quad] + erq;           // 1-line broadcast gather
        x = (x > 0.f) ? x : ALPHA * x;
        float wgt = __expf(x);
        s += wgt;
        float2 raw = ((const float2*)fth)[(size_t)sv * 64 + lane];
        __half2 h0 = *reinterpret_cast<const __half2*>(&raw.x);
        __half2 h1 = *reinterpret_cast<const __half2*>(&raw.y);
        a0 = fmaf(wgt, __low2float(h0), a0);
        a1 = fmaf(wgt, __high2float(h0), a1);
        a2 = fmaf(wgt, __low2float(h1), a2);
        a3 = fmaf(wgt, __high2float(h1), a3);
    }
    float invd = (deg > 0 && s > 0.f) ? 1.f / s : 0.f;
    f32x4 o;
    o[0] = a0 * invd; o[1] = a1 * invd; o[2] = a2 * invd; o[3] = a3 * invd;
    __builtin_nontemporal_store(o, (f32x4*)out + (size_t)wid * 64 + lane);
}

// ---------------- launch ----------------
extern "C" void kernel_launch(void* const* d_in, const int* in_sizes, int n_in,
                              void* d_out, int out_size, void* d_ws, size_t ws_size,
                              hipStream_t stream) {
    const float* feat = (const float*)d_in[0];
    const float* fc_w = (const float*)d_in[1];
    const float* attn_l = (const float*)d_in[2];
    const float* attn_r = (const float*)d_in[3];
    const int* src = (const int*)d_in[4];
    const int* dst = (const int*)d_in[5];
    float* out = (float*)d_out;

    char* w = (char*)d_ws;
    unsigned short* fth = (unsigned short*)w;  w += (size_t)N_NODES * HD * 2;      // 25.6 MB (f16)
    unsigned short* Bt = (unsigned short*)w;   w += (size_t)IN_F * HD * 2;         // 128 KB (bf16)
    float* el = (float*)w;       w += (size_t)N_NODES * NH * 4;                    // 800 KB
    float* er = (float*)w;       w += (size_t)N_NODES * NH * 4;                    // 800 KB
    unsigned short* hist16 = (unsigned short*)w;  w += (size_t)NHB * N_NODES * 2;  // 4.9 MB
    int* counts = (int*)w;       w += (size_t)N_NODES * 4;
    int* offs = (int*)w;         w += (size_t)N_NODES * 4;
    int* gcursor = (int*)w;      w += 256;
    unsigned short* erank16 = (unsigned short*)w; w += (size_t)N_EDGES * 2;        // 1.6 MB
    int* esrc = (int*)w;         w += (size_t)N_EDGES * 4;                          // 3.2 MB

    // pre: 49 hist blocks + 128 cvt blocks (one dispatch)
    k_pre<<<NHB + 128, 512, 0, stream>>>(fc_w, Bt, dst, hist16, erank16, gcursor);

    k_scan<<<(N_NODES + 511) / 512, 512, 0, stream>>>(hist16, counts, offs,
                                                      gcursor, N_NODES);

    // main: 196 gemm blocks + 196 scatter blocks (scatter hides under gemm)
    k_main<<<GEMMB + SCATB, 512, 0, stream>>>(feat, Bt, fth, el, er, attn_l, attn_r,
                                              src, dst, hist16, offs, erank16,
                                              esrc, N_NODES);

    int agg_blocks = (N_NODES * 64 + 255) / 256;
    k_agg<<<agg_blocks, 256, 0, stream>>>(fth, el, er, offs, counts, esrc, out, N_NODES);
}

// Round 23
// 132.764 us; speedup vs baseline: 1.2453x; 1.0740x over previous
//
#include <hip/hip_runtime.h>
#include <hip/hip_bf16.h>
#include <hip/hip_fp16.h>

#define N_NODES 50000
#define N_EDGES 800000
#define IN_F 256
#define NH 4
#define DH 64
#define HD 256
#define ALPHA 0.2f
#define EPB 16384                                  // edges per hist block (2^14)
#define NHB ((N_EDGES + EPB - 1) / EPB)            // 49 hist blocks / copies
#define GEMMB ((N_NODES + 255) / 256)              // 196 gemm blocks (BM=256)
#define SCATB ((N_EDGES / 8 + 511) / 512)          // 196 scatter blocks
#define FCVB (N_NODES * HD / 8 / 512)              // 3125 feat-cvt blocks

typedef short bf16x8 __attribute__((ext_vector_type(8)));
typedef float f32x4 __attribute__((ext_vector_type(4)));

__device__ __forceinline__ unsigned short f2bf(float f) {
    unsigned u = __float_as_uint(f);
    u = (u + 0x7FFFu + ((u >> 16) & 1u)) >> 16;   // RNE
    return (unsigned short)u;
}

// ---------------- PRE: hist (0..48) | Bt cvt (49..176) | feat cvt (177..3301) ----
// HIST: block b owns edges [b*EPB, b*EPB+EPB); full node histogram in LDS as
// packed 2xu16 (100 KB). LDS atomicAdd returns rank -> erank16[e]; packed cnt
// array IS the u16 hist layout -> raw int4 dump.
// BT CVT: Bt[n][k] = bf16(fw[k][n]); also resets gcursor.
// FEAT CVT: fb = bf16(feat), streaming 8 elems/thread -> gemm reads bf16 A
// directly (no per-block f2bf VALU, A traffic halved).
__global__ __launch_bounds__(512) void k_pre(const float* __restrict__ fw,
                                             unsigned short* __restrict__ Bt,
                                             const float* __restrict__ feat,
                                             unsigned short* __restrict__ fb,
                                             const int* __restrict__ dst,
                                             unsigned short* __restrict__ hist16,
                                             unsigned short* __restrict__ erank16,
                                             int* __restrict__ gcursor) {
    __shared__ int cnt[N_NODES / 2];               // 100 KB (hist blocks only)
    const int tid = threadIdx.x;

    if (blockIdx.x >= NHB + 128) {
        // -------- feat convert block --------
        int t = (blockIdx.x - (NHB + 128)) * 512 + tid;   // < 1.6M
        const float* sp = feat + (size_t)t * 8;
        float4 lo = *(const float4*)sp;
        float4 hi = *(const float4*)(sp + 4);
        bf16x8 v;
        v[0] = (short)f2bf(lo.x); v[1] = (short)f2bf(lo.y);
        v[2] = (short)f2bf(lo.z); v[3] = (short)f2bf(lo.w);
        v[4] = (short)f2bf(hi.x); v[5] = (short)f2bf(hi.y);
        v[6] = (short)f2bf(hi.z); v[7] = (short)f2bf(hi.w);
        *(bf16x8*)(fb + (size_t)t * 8) = v;
        return;
    }

    if (blockIdx.x >= NHB) {
        // -------- Bt convert block --------
        if (blockIdx.x == NHB && tid == 0) *gcursor = 0;
        int t = (blockIdx.x - NHB) * 512 + tid;    // 0..65535
        int n = t >> 8, k = t & 255;
        Bt[n * 256 + k] = f2bf(fw[k * 256 + n]);
        return;
    }

    // -------- histogram block --------
    const int b = blockIdx.x;
    for (int i = tid; i < N_NODES / 2; i += 512) cnt[i] = 0;
    __syncthreads();
    const int e0 = b * EPB;
    const int eend = min(e0 + EPB, N_EDGES);
    for (int e = e0 + tid; e < eend; e += 512) {
        int d = dst[e];
        int old = atomicAdd(&cnt[d >> 1], (d & 1) ? (1 << 16) : 1);
        erank16[e] = (unsigned short)((d & 1) ? ((old >> 16) & 0xffff) : (old & 0xffff));
    }
    __syncthreads();
    int4* hb = (int4*)(hist16 + (size_t)b * N_NODES);
    for (int i = tid; i < N_NODES / 8; i += 512)
        hb[i] = ((const int4*)cnt)[i];
}

// ---------------- fused scan: per-copy u16 prefixes + unordered segment alloc ----
__global__ __launch_bounds__(512) void k_scan(unsigned short* __restrict__ hist16,
                                              int* __restrict__ counts,
                                              int* __restrict__ offs,
                                              int* __restrict__ gcursor, int N) {
    __shared__ int sm[512];
    __shared__ int sbase;
    int i = blockIdx.x * 512 + threadIdx.x;
    int v = 0;
    if (i < N) {
        int pf = 0;
        for (int c = 0; c < NHB; c++) {
            unsigned short* p = hist16 + (size_t)c * N_NODES + i;
            int t = *p;
            *p = (unsigned short)pf;
            pf += t;
        }
        v = pf;
        counts[i] = v;
    }
    sm[threadIdx.x] = v;
    __syncthreads();
    for (int off = 1; off < 512; off <<= 1) {
        int t = (threadIdx.x >= off) ? sm[threadIdx.x - off] : 0;
        __syncthreads();
        sm[threadIdx.x] += t;
        __syncthreads();
    }
    if (threadIdx.x == 511) sbase = atomicAdd(gcursor, sm[511]);
    __syncthreads();
    if (i < N) offs[i] = sbase + sm[threadIdx.x] - v;
}

// ---------------- MAIN: blocks 0..195 = GEMM (BM=256, bf16 A), 196.. = scatter ----
__global__ __launch_bounds__(512) void k_main(const unsigned short* __restrict__ fb,
                                              const unsigned short* __restrict__ Bt,
                                              unsigned short* __restrict__ fth,
                                              float* __restrict__ el,
                                              float* __restrict__ er,
                                              const float* __restrict__ al,
                                              const float* __restrict__ ar,
                                              const int* __restrict__ src,
                                              const int* __restrict__ dst,
                                              const unsigned short* __restrict__ hist16,
                                              const int* __restrict__ offs,
                                              const unsigned short* __restrict__ erank16,
                                              int* __restrict__ esrc, int M) {
    __shared__ __align__(16) char smem[131072];
    const int tid = threadIdx.x;

    if (blockIdx.x >= GEMMB) {
        // -------- scatter block: 8 edges/thread --------
        int t = (blockIdx.x - GEMMB) * 512 + tid;
        if (t < N_EDGES / 8) {
            int e = t * 8;
            const unsigned short* hp = hist16 + (size_t)(e >> 14) * N_NODES;
            int4 da = *(const int4*)(dst + e);
            int4 db = *(const int4*)(dst + e + 4);
            int4 sa = *(const int4*)(src + e);
            int4 sb = *(const int4*)(src + e + 4);
            ushort4 ra = *(const ushort4*)(erank16 + e);
            ushort4 rb = *(const ushort4*)(erank16 + e + 4);
            esrc[hp[da.x] + offs[da.x] + ra.x] = sa.x;
            esrc[hp[da.y] + offs[da.y] + ra.y] = sa.y;
            esrc[hp[da.z] + offs[da.z] + ra.z] = sa.z;
            esrc[hp[da.w] + offs[da.w] + ra.w] = sa.w;
            esrc[hp[db.x] + offs[db.x] + rb.x] = sb.x;
            esrc[hp[db.y] + offs[db.y] + rb.y] = sb.y;
            esrc[hp[db.z] + offs[db.z] + rb.z] = sb.z;
            esrc[hp[db.w] + offs[db.w] + rb.w] = sb.w;
        }
        return;
    }

    // -------- GEMM block (BM=256, bf16 A) --------
    const int m0 = blockIdx.x * 256;

    #pragma unroll
    for (int c = 0; c < 16; c++) {
        int o = c * 8192 + tid * 16;            // byte offset
        bf16x8 v = *(const bf16x8*)((const char*)Bt + o);
        int nl = o >> 9;
        int lb = o ^ ((nl & 7) << 4);
        *(bf16x8*)(smem + lb) = v;
    }
    __syncthreads();

    const int w = tid >> 6, lane = tid & 63;
    const int wm = w >> 2, wn = w & 3;          // 2 x 4; wave: 128 rows x 64 cols (head wn)
    const int fr = lane & 15, quad = lane >> 4;

    const unsigned short* arow[8];
    int gm[8];
    #pragma unroll
    for (int j = 0; j < 8; j++) {
        gm[j] = m0 + wm * 128 + j * 16 + fr;
        int cr = gm[j] < M ? gm[j] : (M - 1);
        arow[j] = fb + (size_t)cr * IN_F;
    }

    f32x4 acc[8][4];
    #pragma unroll
    for (int j = 0; j < 8; j++)
        #pragma unroll
        for (int f = 0; f < 4; f++) acc[j][f] = (f32x4){0.f, 0.f, 0.f, 0.f};

    #pragma unroll
    for (int kk = 0; kk < 8; kk++) {
        bf16x8 af[8];
        #pragma unroll
        for (int j = 0; j < 8; j++)
            af[j] = *(const bf16x8*)(arow[j] + kk * 32 + quad * 8);
        #pragma unroll
        for (int f = 0; f < 4; f++) {
            int nl = wn * 64 + f * 16 + fr;
            int lb = (nl * 512 + (kk * 32 + quad * 8) * 2) ^ ((nl & 7) << 4);
            bf16x8 bfr = *(const bf16x8*)(smem + lb);
            #pragma unroll
            for (int j = 0; j < 8; j++)
                acc[j][f] = __builtin_amdgcn_mfma_f32_16x16x32_bf16(bfr, af[j], acc[j][f], 0, 0, 0);
        }
    }
    // lane holds D[row = m0+wm*128+j*16+fr][col = wn*64+f*16+quad*4+r]

    // fused el/er (head wn)
    #pragma unroll
    for (int j = 0; j < 8; j++) {
        float pl = 0.f, pr = 0.f;
        #pragma unroll
        for (int f = 0; f < 4; f++) {
            float4 a4 = *(const float4*)(al + wn * 64 + f * 16 + quad * 4);
            float4 b4 = *(const float4*)(ar + wn * 64 + f * 16 + quad * 4);
            pl += acc[j][f][0] * a4.x + acc[j][f][1] * a4.y + acc[j][f][2] * a4.z + acc[j][f][3] * a4.w;
            pr += acc[j][f][0] * b4.x + acc[j][f][1] * b4.y + acc[j][f][2] * b4.z + acc[j][f][3] * b4.w;
        }
        pl += __shfl_xor(pl, 16); pl += __shfl_xor(pl, 32);
        pr += __shfl_xor(pr, 16); pr += __shfl_xor(pr, 32);
        if (quad == 0 && gm[j] < M) {
            el[gm[j] * NH + wn] = pl;
            er[gm[j] * NH + wn] = pr;
        }
    }

    // direct f16 stores
    #pragma unroll
    for (int j = 0; j < 8; j++) {
        if (gm[j] < M) {
            unsigned short* dp = fth + (size_t)gm[j] * HD + wn * 64 + quad * 4;
            #pragma unroll
            for (int f = 0; f < 4; f++) {
                ushort4 pk;
                pk.x = __half_as_ushort(__float2half(acc[j][f][0]));
                pk.y = __half_as_ushort(__float2half(acc[j][f][1]));
                pk.z = __half_as_ushort(__float2half(acc[j][f][2]));
                pk.w = __half_as_ushort(__float2half(acc[j][f][3]));
                *(ushort4*)(dp + f * 16) = pk;
            }
        }
    }
}

// ---------------- Aggregation: one wave per dst node, SINGLE PASS ----------------
__global__ __launch_bounds__(256) void k_agg(const unsigned short* __restrict__ fth,
                                             const float* __restrict__ el,
                                             const float* __restrict__ er,
                                             const int* __restrict__ offs,
                                             const int* __restrict__ counts,
                                             const int* __restrict__ esrc,
                                             float* __restrict__ out, int N) {
    int wid = (blockIdx.x * 256 + threadIdx.x) >> 6;
    const int lane = threadIdx.x & 63;
    if (wid >= N) return;
    const int deg = counts[wid];
    const int start = offs[wid];
    const int quad = lane >> 4;                 // head of my 4 cols
    const float erq = er[wid * NH + quad];

    float s = 0.f;
    float a0 = 0.f, a1 = 0.f, a2 = 0.f, a3 = 0.f;
    #pragma unroll 4
    for (int i = 0; i < deg; i++) {
        int sv = esrc[start + i];                     // wave-uniform
        float x = el[sv * NH + quad] + erq;           // 1-line broadcast gather
        x = (x > 0.f) ? x : ALPHA * x;
        float wgt = __expf(x);
        s += wgt;
        float2 raw = ((const float2*)fth)[(size_t)sv * 64 + lane];
        __half2 h0 = *reinterpret_cast<const __half2*>(&raw.x);
        __half2 h1 = *reinterpret_cast<const __half2*>(&raw.y);
        a0 = fmaf(wgt, __low2float(h0), a0);
        a1 = fmaf(wgt, __high2float(h0), a1);
        a2 = fmaf(wgt, __low2float(h1), a2);
        a3 = fmaf(wgt, __high2float(h1), a3);
    }
    float invd = (deg > 0 && s > 0.f) ? 1.f / s : 0.f;
    f32x4 o;
    o[0] = a0 * invd; o[1] = a1 * invd; o[2] = a2 * invd; o[3] = a3 * invd;
    __builtin_nontemporal_store(o, (f32x4*)out + (size_t)wid * 64 + lane);
}

// ---------------- launch ----------------
extern "C" void kernel_launch(void* const* d_in, const int* in_sizes, int n_in,
                              void* d_out, int out_size, void* d_ws, size_t ws_size,
                              hipStream_t stream) {
    const float* feat = (const float*)d_in[0];
    const float* fc_w = (const float*)d_in[1];
    const float* attn_l = (const float*)d_in[2];
    const float* attn_r = (const float*)d_in[3];
    const int* src = (const int*)d_in[4];
    const int* dst = (const int*)d_in[5];
    float* out = (float*)d_out;

    char* w = (char*)d_ws;
    unsigned short* fth = (unsigned short*)w;  w += (size_t)N_NODES * HD * 2;      // 25.6 MB (f16)
    unsigned short* fb = (unsigned short*)w;   w += (size_t)N_NODES * IN_F * 2;    // 25.6 MB (bf16 A)
    unsigned short* Bt = (unsigned short*)w;   w += (size_t)IN_F * HD * 2;         // 128 KB (bf16)
    float* el = (float*)w;       w += (size_t)N_NODES * NH * 4;                    // 800 KB
    float* er = (float*)w;       w += (size_t)N_NODES * NH * 4;                    // 800 KB
    unsigned short* hist16 = (unsigned short*)w;  w += (size_t)NHB * N_NODES * 2;  // 4.9 MB
    int* counts = (int*)w;       w += (size_t)N_NODES * 4;
    int* offs = (int*)w;         w += (size_t)N_NODES * 4;
    int* gcursor = (int*)w;      w += 256;
    unsigned short* erank16 = (unsigned short*)w; w += (size_t)N_EDGES * 2;        // 1.6 MB
    int* esrc = (int*)w;         w += (size_t)N_EDGES * 4;                          // 3.2 MB

    // pre: 49 hist + 128 Bt-cvt + 3125 feat-cvt blocks (one dispatch)
    k_pre<<<NHB + 128 + FCVB, 512, 0, stream>>>(fc_w, Bt, feat, fb, dst,
                                                hist16, erank16, gcursor);

    k_scan<<<(N_NODES + 511) / 512, 512, 0, stream>>>(hist16, counts, offs,
                                                      gcursor, N_NODES);

    // main: 196 gemm blocks + 196 scatter blocks
    k_main<<<GEMMB + SCATB, 512, 0, stream>>>(fb, Bt, fth, el, er, attn_l, attn_r,
                                              src, dst, hist16, offs, erank16,
                                              esrc, N_NODES);

    int agg_blocks = (N_NODES * 64 + 255) / 256;
    k_agg<<<agg_blocks, 256, 0, stream>>>(fth, el, er, offs, counts, esrc, out, N_NODES);
}